// Round 9
// baseline (62.794 us; speedup 1.0000x reference)
//
#include <hip/hip_runtime.h>
#include <math.h>

#define N1 1024
#define DPROJ 1024
#define M_NODES 4368
#define N2 (N1 + M_NODES)      // 5392
#define N2P 5504               // padded to 43*128 for the GEMM
#define L_LEAVES 4096
#define INV_T (1.0f / 0.07f)
#define NBX 43                 // N2P / BN

typedef __bf16 bf16;
typedef __bf16 bf16x4v __attribute__((ext_vector_type(4)));
typedef __bf16 bf16x8 __attribute__((ext_vector_type(8)));
typedef float f32x4 __attribute__((ext_vector_type(4)));

// ---------------------------------------------------------------------------
// Kernel A: fused normalize + bf16 cast. kn[row] = row/max(||row||,1e-12);
// rows >= N2 zero-filled (GEMM padding). Block 0 also zeroes d_out.
// ---------------------------------------------------------------------------
__global__ __launch_bounds__(256) void normalize_kernel(
    const float* __restrict__ q, const float* __restrict__ vc,
    bf16* __restrict__ kn, float* __restrict__ out) {
  const int row = blockIdx.x;
  if (row == 0 && threadIdx.x == 0) { out[0] = 0.f; out[1] = 0.f; }
  bf16x4v* dst = (bf16x4v*)(kn + (size_t)row * DPROJ);
  if (row >= N2) {
    bf16x4v z = {(bf16)0.f, (bf16)0.f, (bf16)0.f, (bf16)0.f};
    dst[threadIdx.x] = z;
    return;
  }
  const float* src = (row < N1) ? q + (size_t)row * DPROJ
                                : vc + (size_t)(row - N1) * DPROJ;
  float4 v = ((const float4*)src)[threadIdx.x];
  float s = v.x * v.x + v.y * v.y + v.z * v.z + v.w * v.w;
  for (int off = 32; off > 0; off >>= 1) s += __shfl_down(s, off);
  __shared__ float wsum[4];
  const int lane = threadIdx.x & 63, wid = threadIdx.x >> 6;
  if (lane == 0) wsum[wid] = s;
  __syncthreads();
  const float tot = wsum[0] + wsum[1] + wsum[2] + wsum[3];
  const float inv = 1.0f / fmaxf(sqrtf(tot), 1e-12f);
  bf16x4v o = {(bf16)(v.x * inv), (bf16)(v.y * inv), (bf16)(v.z * inv),
               (bf16)(v.w * inv)};
  dst[threadIdx.x] = o;
}

// ---------------------------------------------------------------------------
// Kernel B: fused GEMM + loss partials.
// R9: 2-wave (128-thread) blocks, wave tile 64x64 (acc 4x4) -> 16 MFMA :
// 8 ds_read_b128 per iter (2:1 vs R8's 1.33:1); LDS 39.75 KB -> 4 blocks/CU
// (4 independent blocks = more async TLP; barriers converge 2 waves not 4).
// Same 688-block grid, same R8 sync (3 bufs, 2-ahead prefetch, counted
// vmcnt(6), raw s_barriers), same R7 XOR swizzle (row shifts are 0 mod 8 so
// the read-slot formula is unchanged). T5 setprio around the MFMA cluster
// (4 independent blocks/CU = wave role diversity).
// ---------------------------------------------------------------------------
#define BM 64
#define BN 128
#define BK 32
#define NT (DPROJ / BK)

__device__ __forceinline__ void gload16(const bf16* g, bf16* l) {
  __builtin_amdgcn_global_load_lds(
      (const __attribute__((address_space(1))) void*)g,
      (__attribute__((address_space(3))) void*)l, 16, 0, 0);
}

__global__ __launch_bounds__(128, 2) void gemm_loss_kernel(
    const bf16* __restrict__ kn, const int* __restrict__ labels,
    float* __restrict__ partials) {
  __shared__ bf16 As[3][BM][BK];         // 12 KB
  __shared__ bf16 Bs[3][BN][BK];         // 24 KB
  __shared__ int lab_r[BM];              // 256 B
  __shared__ int lab_c[BN];              // 512 B
  __shared__ float blk_part[BM][2][6];   // 3 KB
  const int bx = blockIdx.x;
  const int j0 = bx * BN;
  const int i0 = blockIdx.y * BM;
  const int t = threadIdx.x;
  const int lane = t & 63, w = t >> 6;   // w in {0,1}
  const int wn = w;                      // wave covers cols [wn*64, wn*64+64)

  if (t < BM) lab_r[t] = labels[i0 + t];
  if (j0 < N1) lab_c[t] = labels[j0 + t];

  f32x4 acc[4][4] = {};

  // Staging: each gload covers 16 rows (lane>>2) x 4 16B-slots (lane&3).
  // Wave w: A rows w*32+{0,16}; B rows w*64+{0,16,32,48}. Global slot
  // pre-swizzled: (lane&3) ^ ((row>>1)&3) = ^((lane>>3)&3) (R7 involution).
  const int rik = lane >> 2;
  const int kswz = ((lane & 3) ^ ((lane >> 3) & 3)) * 8;
  const bf16* gA0 = kn + (size_t)(i0 + w * 32 + rik) * DPROJ + kswz;
  const bf16* gA1 = gA0 + (size_t)16 * DPROJ;
  const bf16* gB0 = kn + (size_t)(j0 + w * 64 + rik) * DPROJ + kswz;
  const bf16* gB1 = gB0 + (size_t)16 * DPROJ;
  const bf16* gB2 = gB0 + (size_t)32 * DPROJ;
  const bf16* gB3 = gB0 + (size_t)48 * DPROJ;

  // Fragment reads: wave reads ALL 64 A-rows (m=0..3) and its 64 B-cols.
  // row = (lane&15) + 16*m (shifts 0 mod 8 -> same swizzle for all m,n):
  // LDS slot = (lane>>4) ^ ((lane>>1)&3). Conflict-free (R7-measured).
  const int ar = lane & 15;
  const int br = wn * 64 + (lane & 15);
  const int kf = (((lane >> 4) ^ ((lane >> 1) & 3))) * 8;

#define STAGE(buf, k0)                                   \
  do {                                                   \
    gload16(gA0 + (k0), &As[buf][w * 32][0]);            \
    gload16(gA1 + (k0), &As[buf][w * 32 + 16][0]);       \
    gload16(gB0 + (k0), &Bs[buf][w * 64][0]);            \
    gload16(gB1 + (k0), &Bs[buf][w * 64 + 16][0]);       \
    gload16(gB2 + (k0), &Bs[buf][w * 64 + 32][0]);       \
    gload16(gB3 + (k0), &Bs[buf][w * 64 + 48][0]);       \
  } while (0)

  // Prologue: tiles 0,1 into bufs 0,1; full drain (also labels visible).
  STAGE(0, 0);
  STAGE(1, BK);
  __syncthreads();

#pragma unroll 3
  for (int it = 0; it < NT; ++it) {
    const int cur = it % 3;
    if (it + 2 < NT) {
      STAGE((it + 2) % 3, (it + 2) * BK);
      asm volatile("s_waitcnt vmcnt(6)" ::: "memory");   // oldest 6 done
    } else if (it + 1 < NT) {
      asm volatile("s_waitcnt vmcnt(6)" ::: "memory");
    } else {
      asm volatile("s_waitcnt vmcnt(0)" ::: "memory");
    }
    __builtin_amdgcn_s_barrier();   // all waves' tile-it loads complete

    bf16x8 a[4], b[4];
#pragma unroll
    for (int m = 0; m < 4; ++m)
      a[m] = *(const bf16x8*)&As[cur][ar + m * 16][kf];
#pragma unroll
    for (int n = 0; n < 4; ++n)
      b[n] = *(const bf16x8*)&Bs[cur][br + n * 16][kf];
    __builtin_amdgcn_s_setprio(1);
#pragma unroll
    for (int m = 0; m < 4; ++m)
#pragma unroll
      for (int n = 0; n < 4; ++n)
        acc[m][n] = __builtin_amdgcn_mfma_f32_16x16x32_bf16(
            a[m], b[n], acc[m][n], 0, 0, 0);
    __builtin_amdgcn_s_setprio(0);

    __builtin_amdgcn_s_barrier();   // reads of buf[cur] done -> reusable
  }

  // Fused epilogue. C/D layout: col=lane&15, row=(lane>>4)*4+j [m89].
  const int g = lane >> 4;
  const int p = lane & 15;
#pragma unroll
  for (int m = 0; m < 4; ++m) {
#pragma unroll
    for (int j = 0; j < 4; ++j) {
      const int rloc = m * 16 + g * 4 + j;
      const int lab = lab_r[rloc];
      const int a2 = lab >> 4, a1 = lab >> 8;
      float ps0 = 0, ps1 = 0, ps2 = 0, ns0 = 0, ns1 = 0, ns2 = 0;
#pragma unroll
      for (int n = 0; n < 4; ++n) {
        const int cloc = wn * 64 + n * 16 + p;
        const int gc = j0 + cloc;
        if (gc < N2) {
          const int nid = (gc < N1) ? lab_c[cloc] : (gc - N1);
          const bool isLeaf = nid < L_LEAVES;
          const bool isD2 = (nid >= L_LEAVES) && (nid < L_LEAVES + 256);
          const bool eq = (nid == lab);
          const bool inS2 =
              (nid == L_LEAVES + a2) || (isLeaf && ((nid >> 4) == a2));
          const bool inS1 = (nid == L_LEAVES + 256 + a1) ||
                            (isD2 && (((nid - L_LEAVES) >> 4) == a1)) ||
                            (isLeaf && ((nid >> 8) == a1));
          const float v = acc[m][n][j] * INV_T;
          const float e = __expf(v);
          if (eq) ps2 += v; else ns2 += e;
          if (inS2) { if (!eq) ps1 += v; } else ns1 += e;
          if (inS1) { if (!inS2) ps0 += v; } else ns0 += e;
        }
      }
#pragma unroll
      for (int msk = 1; msk < 16; msk <<= 1) {
        ps0 += __shfl_xor(ps0, msk);
        ps1 += __shfl_xor(ps1, msk);
        ps2 += __shfl_xor(ps2, msk);
        ns0 += __shfl_xor(ns0, msk);
        ns1 += __shfl_xor(ns1, msk);
        ns2 += __shfl_xor(ns2, msk);
      }
      if (p == 0) {
        float* d = &blk_part[rloc][wn][0];
        d[0] = ps0; d[1] = ps1; d[2] = ps2;
        d[3] = ns0; d[4] = ns1; d[5] = ns2;
      }
    }
  }
  __syncthreads();
  for (int idx = t; idx < BM * 6; idx += 128) {
    const int r = idx / 6, k = idx % 6;
    const float val = blk_part[r][0][k] + blk_part[r][1][k];
    partials[((size_t)(i0 + r) * NBX + bx) * 6 + k] = val;
  }
}

// ---------------------------------------------------------------------------
// Kernel C: finalize. LDS label histogram, sum 43 slices/row, CE with
// analytic counts: |eq|=hist[lab]+1; |S2|=hist2+17; |S1|=hist1+273.
// Masked entries contribute exp(0)=1 -> +|set| in the LSE.
// ---------------------------------------------------------------------------
__global__ __launch_bounds__(256) void finalize_kernel(
    const float* __restrict__ partials, const int* __restrict__ labels,
    const float* __restrict__ depth, float* __restrict__ out) {
  __shared__ int hist_s[M_NODES];   // 17.4 KB
  const int t = threadIdx.x;
  for (int i = t; i < M_NODES; i += 256) hist_s[i] = 0;
  __syncthreads();
  for (int i = t; i < N1; i += 256) {
    const int lb = labels[i];
    atomicAdd(&hist_s[lb], 1);
    atomicAdd(&hist_s[L_LEAVES + (lb >> 4)], 1);
    atomicAdd(&hist_s[L_LEAVES + 256 + (lb >> 8)], 1);
  }
  __syncthreads();

  const int row = blockIdx.x * 256 + t;
  const int lab = labels[row];
  const int a2 = lab >> 4, a1 = lab >> 8;
  const int cEq = hist_s[lab] + 1;
  const int cS2 = hist_s[L_LEAVES + a2] + 17;
  const int cS1 = hist_s[L_LEAVES + 256 + a1] + 273;
  float ps0 = 0, ps1 = 0, ps2 = 0, ns0 = 0, ns1 = 0, ns2 = 0;
  const float* pp = partials + (size_t)row * NBX * 6;
  for (int b = 0; b < NBX; ++b) {
    ps0 += pp[b * 6 + 0];
    ps1 += pp[b * 6 + 1];
    ps2 += pp[b * 6 + 2];
    ns0 += pp[b * 6 + 3];
    ns1 += pp[b * 6 + 4];
    ns2 += pp[b * 6 + 5];
  }
  float ce = 0.f;
  {
    float pl = ps2 / fmaxf((float)cEq, 1e-6f);
    ce += logf(ns2 + (float)cEq + __expf(pl)) - pl;
  }
  {
    float pl = ps1 / fmaxf((float)(cS2 - cEq), 1e-6f);
    ce += logf(ns1 + (float)cS2 + __expf(pl)) - pl;
  }
  {
    float pl = ps0 / fmaxf((float)(cS1 - cS2), 1e-6f);
    ce += logf(ns0 + (float)cS1 + __expf(pl)) - pl;
  }
  float contrib = ce / depth[lab] * (3.0f / (float)N1);
  for (int off = 32; off > 0; off >>= 1) contrib += __shfl_down(contrib, off);
  __shared__ float wsum[4];
  const int lane = t & 63, wid = t >> 6;
  if (lane == 0) wsum[wid] = contrib;
  __syncthreads();
  if (t == 0) {
    const float tot = wsum[0] + wsum[1] + wsum[2] + wsum[3];
    atomicAdd(&out[0], tot);
    atomicAdd(&out[1], tot);
  }
}

// ---------------------------------------------------------------------------
extern "C" void kernel_launch(void* const* d_in, const int* in_sizes, int n_in,
                              void* d_out, int out_size, void* d_ws,
                              size_t ws_size, hipStream_t stream) {
  const float* q = (const float*)d_in[0];
  const float* vc = (const float*)d_in[1];
  const int* labels = (const int*)d_in[2];
  const float* depth = (const float*)d_in[6];
  float* out = (float*)d_out;

  bf16* kn = (bf16*)d_ws;  // N2P*DPROJ bf16 = 11.27 MB
  float* partials = (float*)((char*)d_ws + (size_t)N2P * DPROJ * sizeof(bf16));
  // partials: N1 * NBX * 6 floats (~1.06 MB), fully written -> no memset

  normalize_kernel<<<N2P, 256, 0, stream>>>(q, vc, kn, out);

  dim3 grid(N2P / BN, N1 / BM);
  gemm_loss_kernel<<<grid, 128, 0, stream>>>(kn, labels, partials);

  finalize_kernel<<<4, 256, 0, stream>>>(partials, labels, depth, out);
}

// Round 10
// 57.389 us; speedup vs baseline: 1.0942x; 1.0942x over previous
//
#include <hip/hip_runtime.h>
#include <math.h>

#define N1 1024
#define DPROJ 1024
#define M_NODES 4368
#define N2 (N1 + M_NODES)      // 5392
#define N2P 5504               // padded to 43*128 for the GEMM
#define L_LEAVES 4096
#define INV_T (1.0f / 0.07f)
#define NBX 43                 // N2P / BN

typedef __bf16 bf16;
typedef __bf16 bf16x4v __attribute__((ext_vector_type(4)));
typedef __bf16 bf16x8 __attribute__((ext_vector_type(8)));
typedef float f32x4 __attribute__((ext_vector_type(4)));

// ---------------------------------------------------------------------------
// Kernel A: fused normalize + bf16 cast. kn[row] = row/max(||row||,1e-12);
// rows >= N2 zero-filled (GEMM padding). Block 0 also zeroes d_out.
// ---------------------------------------------------------------------------
__global__ __launch_bounds__(256) void normalize_kernel(
    const float* __restrict__ q, const float* __restrict__ vc,
    bf16* __restrict__ kn, float* __restrict__ out) {
  const int row = blockIdx.x;
  if (row == 0 && threadIdx.x == 0) { out[0] = 0.f; out[1] = 0.f; }
  bf16x4v* dst = (bf16x4v*)(kn + (size_t)row * DPROJ);
  if (row >= N2) {
    bf16x4v z = {(bf16)0.f, (bf16)0.f, (bf16)0.f, (bf16)0.f};
    dst[threadIdx.x] = z;
    return;
  }
  const float* src = (row < N1) ? q + (size_t)row * DPROJ
                                : vc + (size_t)(row - N1) * DPROJ;
  float4 v = ((const float4*)src)[threadIdx.x];
  float s = v.x * v.x + v.y * v.y + v.z * v.z + v.w * v.w;
  for (int off = 32; off > 0; off >>= 1) s += __shfl_down(s, off);
  __shared__ float wsum[4];
  const int lane = threadIdx.x & 63, wid = threadIdx.x >> 6;
  if (lane == 0) wsum[wid] = s;
  __syncthreads();
  const float tot = wsum[0] + wsum[1] + wsum[2] + wsum[3];
  const float inv = 1.0f / fmaxf(sqrtf(tot), 1e-12f);
  bf16x4v o = {(bf16)(v.x * inv), (bf16)(v.y * inv), (bf16)(v.z * inv),
               (bf16)(v.w * inv)};
  dst[threadIdx.x] = o;
}

// ---------------------------------------------------------------------------
// Kernel B: fused GEMM + loss partials. R8 geometry (64x128 tile, BK=32,
// 2x2 waves of 32x64, 256 threads, 688 blocks, R7 XOR swizzle) — R9's
// 2-wave/64x64 variant regressed (lost TLP) and is reverted.
// R10 change (ONLY): 4 LDS buffers, 3-tiles-ahead prefetch, ONE barrier
// per iteration. STAGE at iter it (AFTER the barrier) writes
// buf[(it+3)&3] = buf[(it-1)&3]; every wave arrives at barrier A_it only
// after completing its iter-(it-1) ds_reads (lgkmcnt < MFMA < arrival),
// so the post-MFMA barrier is redundant and removed. Loads get ~3
// iterations of slack (vs 1). lab_s[1024] -> lab_r[64]+lab_c[128] keeps
// LDS at 51.75 KB -> 3 blocks/CU (12 waves/CU).
// ---------------------------------------------------------------------------
#define BM 64
#define BN 128
#define BK 32
#define NT (DPROJ / BK)

__device__ __forceinline__ void gload16(const bf16* g, bf16* l) {
  __builtin_amdgcn_global_load_lds(
      (const __attribute__((address_space(1))) void*)g,
      (__attribute__((address_space(3))) void*)l, 16, 0, 0);
}

__global__ __launch_bounds__(256, 3) void gemm_loss_kernel(
    const bf16* __restrict__ kn, const int* __restrict__ labels,
    float* __restrict__ partials) {
  __shared__ bf16 As[4][BM][BK];         // 16 KB
  __shared__ bf16 Bs[4][BN][BK];         // 32 KB
  __shared__ int lab_r[BM];              // 256 B
  __shared__ int lab_c[BN];              // 512 B
  __shared__ float blk_part[BM][2][6];   // 3 KB
  const int bx = blockIdx.x;
  const int j0 = bx * BN;
  const int i0 = blockIdx.y * BM;
  const int t = threadIdx.x;
  const int lane = t & 63, w = t >> 6;
  const int wm = w >> 1, wn = w & 1;   // wave grid 2x2, wave tile 32x64

  if (t < BM) lab_r[t] = labels[i0 + t];
  if (t < BN && j0 + t < N1) lab_c[t] = labels[j0 + t];

  f32x4 acc[2][4] = {};

  // Staging: wave w stages A rows [16w,16w+16) and B rows {16w, 16w+64}.
  // lane -> row = lane>>2, LDS 16B-slot = lane&3 (linear dest).
  // Global 16B-slot pre-swizzled: (lane&3) ^ ((row>>1)&3) = ^((lane>>3)&3).
  const int rik = lane >> 2;
  const int kswz = ((lane & 3) ^ ((lane >> 3) & 3)) * 8;
  const bf16* gA = kn + (size_t)(i0 + w * 16 + rik) * DPROJ + kswz;
  const bf16* gB0 = kn + (size_t)(j0 + w * 16 + rik) * DPROJ + kswz;
  const bf16* gB1 = gB0 + (size_t)64 * DPROJ;

  // Fragment reads: row = base + (lane&15), logical k-slot g = lane>>4 ->
  // LDS slot g ^ ((row>>1)&3). Conflict-free (R7-measured).
  const int ar = wm * 32 + (lane & 15);
  const int br = wn * 64 + (lane & 15);
  const int kf = (((lane >> 4) ^ ((lane >> 1) & 3))) * 8;

#define STAGE(buf, k0)                            \
  do {                                            \
    gload16(gA + (k0), &As[buf][w * 16][0]);      \
    gload16(gB0 + (k0), &Bs[buf][w * 16][0]);     \
    gload16(gB1 + (k0), &Bs[buf][w * 16 + 64][0]);\
  } while (0)

  // Prologue: stage tiles 0,1,2 into bufs 0,1,2 (9 loads/wave in flight).
  STAGE(0, 0);
  STAGE(1, BK);
  STAGE(2, 2 * BK);

#pragma unroll 4
  for (int it = 0; it < NT; ++it) {
    const int cur = it & 3;
    // Wait for this wave's own tile-it loads (oldest 3), then barrier:
    // all waves' tile-it loads complete; all waves' iter-(it-1) LDS reads
    // complete (program order) -> safe to overwrite buf[(it-1)&3].
    if (it <= NT - 3) {
      asm volatile("s_waitcnt vmcnt(6)" ::: "memory");
    } else if (it == NT - 2) {
      asm volatile("s_waitcnt vmcnt(3)" ::: "memory");
    } else {
      asm volatile("s_waitcnt vmcnt(0)" ::: "memory");
    }
    __builtin_amdgcn_s_barrier();

    if (it + 3 < NT) STAGE((it + 3) & 3, (it + 3) * BK);

    bf16x8 a[2], b[4];
#pragma unroll
    for (int m = 0; m < 2; ++m)
      a[m] = *(const bf16x8*)&As[cur][ar + m * 16][kf];
#pragma unroll
    for (int n = 0; n < 4; ++n)
      b[n] = *(const bf16x8*)&Bs[cur][br + n * 16][kf];
#pragma unroll
    for (int m = 0; m < 2; ++m)
#pragma unroll
      for (int n = 0; n < 4; ++n)
        acc[m][n] = __builtin_amdgcn_mfma_f32_16x16x32_bf16(
            a[m], b[n], acc[m][n], 0, 0, 0);
  }

  // Fused epilogue. C/D layout: col=lane&15, row=(lane>>4)*4+j [m89].
  // One barrier so the last tile's reads are done block-wide before we
  // reuse nothing — actually needed only for lab_r/lab_c visibility.
  __builtin_amdgcn_s_barrier();
  const int g = lane >> 4;
  const int p = lane & 15;
#pragma unroll
  for (int m = 0; m < 2; ++m) {
#pragma unroll
    for (int j = 0; j < 4; ++j) {
      const int rloc = wm * 32 + m * 16 + g * 4 + j;
      const int lab = lab_r[rloc];
      const int a2 = lab >> 4, a1 = lab >> 8;
      float ps0 = 0, ps1 = 0, ps2 = 0, ns0 = 0, ns1 = 0, ns2 = 0;
#pragma unroll
      for (int n = 0; n < 4; ++n) {
        const int cloc = wn * 64 + n * 16 + p;
        const int gc = j0 + cloc;
        if (gc < N2) {
          const int nid = (gc < N1) ? lab_c[cloc] : (gc - N1);
          const bool isLeaf = nid < L_LEAVES;
          const bool isD2 = (nid >= L_LEAVES) && (nid < L_LEAVES + 256);
          const bool eq = (nid == lab);
          const bool inS2 =
              (nid == L_LEAVES + a2) || (isLeaf && ((nid >> 4) == a2));
          const bool inS1 = (nid == L_LEAVES + 256 + a1) ||
                            (isD2 && (((nid - L_LEAVES) >> 4) == a1)) ||
                            (isLeaf && ((nid >> 8) == a1));
          const float v = acc[m][n][j] * INV_T;
          const float e = __expf(v);
          if (eq) ps2 += v; else ns2 += e;
          if (inS2) { if (!eq) ps1 += v; } else ns1 += e;
          if (inS1) { if (!inS2) ps0 += v; } else ns0 += e;
        }
      }
#pragma unroll
      for (int msk = 1; msk < 16; msk <<= 1) {
        ps0 += __shfl_xor(ps0, msk);
        ps1 += __shfl_xor(ps1, msk);
        ps2 += __shfl_xor(ps2, msk);
        ns0 += __shfl_xor(ns0, msk);
        ns1 += __shfl_xor(ns1, msk);
        ns2 += __shfl_xor(ns2, msk);
      }
      if (p == 0) {
        float* d = &blk_part[rloc][wn][0];
        d[0] = ps0; d[1] = ps1; d[2] = ps2;
        d[3] = ns0; d[4] = ns1; d[5] = ns2;
      }
    }
  }
  __syncthreads();
  for (int idx = t; idx < BM * 6; idx += 256) {
    const int r = idx / 6, k = idx % 6;
    const float val = blk_part[r][0][k] + blk_part[r][1][k];
    partials[((size_t)(i0 + r) * NBX + bx) * 6 + k] = val;
  }
}

// ---------------------------------------------------------------------------
// Kernel C: finalize. LDS label histogram, sum 43 slices/row, CE with
// analytic counts: |eq|=hist[lab]+1; |S2|=hist2+17; |S1|=hist1+273.
// Masked entries contribute exp(0)=1 -> +|set| in the LSE.
// ---------------------------------------------------------------------------
__global__ __launch_bounds__(256) void finalize_kernel(
    const float* __restrict__ partials, const int* __restrict__ labels,
    const float* __restrict__ depth, float* __restrict__ out) {
  __shared__ int hist_s[M_NODES];   // 17.4 KB
  const int t = threadIdx.x;
  for (int i = t; i < M_NODES; i += 256) hist_s[i] = 0;
  __syncthreads();
  for (int i = t; i < N1; i += 256) {
    const int lb = labels[i];
    atomicAdd(&hist_s[lb], 1);
    atomicAdd(&hist_s[L_LEAVES + (lb >> 4)], 1);
    atomicAdd(&hist_s[L_LEAVES + 256 + (lb >> 8)], 1);
  }
  __syncthreads();

  const int row = blockIdx.x * 256 + t;
  const int lab = labels[row];
  const int a2 = lab >> 4, a1 = lab >> 8;
  const int cEq = hist_s[lab] + 1;
  const int cS2 = hist_s[L_LEAVES + a2] + 17;
  const int cS1 = hist_s[L_LEAVES + 256 + a1] + 273;
  float ps0 = 0, ps1 = 0, ps2 = 0, ns0 = 0, ns1 = 0, ns2 = 0;
  const float* pp = partials + (size_t)row * NBX * 6;
  for (int b = 0; b < NBX; ++b) {
    ps0 += pp[b * 6 + 0];
    ps1 += pp[b * 6 + 1];
    ps2 += pp[b * 6 + 2];
    ns0 += pp[b * 6 + 3];
    ns1 += pp[b * 6 + 4];
    ns2 += pp[b * 6 + 5];
  }
  float ce = 0.f;
  {
    float pl = ps2 / fmaxf((float)cEq, 1e-6f);
    ce += logf(ns2 + (float)cEq + __expf(pl)) - pl;
  }
  {
    float pl = ps1 / fmaxf((float)(cS2 - cEq), 1e-6f);
    ce += logf(ns1 + (float)cS2 + __expf(pl)) - pl;
  }
  {
    float pl = ps0 / fmaxf((float)(cS1 - cS2), 1e-6f);
    ce += logf(ns0 + (float)cS1 + __expf(pl)) - pl;
  }
  float contrib = ce / depth[lab] * (3.0f / (float)N1);
  for (int off = 32; off > 0; off >>= 1) contrib += __shfl_down(contrib, off);
  __shared__ float wsum[4];
  const int lane = t & 63, wid = t >> 6;
  if (lane == 0) wsum[wid] = contrib;
  __syncthreads();
  if (t == 0) {
    const float tot = wsum[0] + wsum[1] + wsum[2] + wsum[3];
    atomicAdd(&out[0], tot);
    atomicAdd(&out[1], tot);
  }
}

// ---------------------------------------------------------------------------
extern "C" void kernel_launch(void* const* d_in, const int* in_sizes, int n_in,
                              void* d_out, int out_size, void* d_ws,
                              size_t ws_size, hipStream_t stream) {
  const float* q = (const float*)d_in[0];
  const float* vc = (const float*)d_in[1];
  const int* labels = (const int*)d_in[2];
  const float* depth = (const float*)d_in[6];
  float* out = (float*)d_out;

  bf16* kn = (bf16*)d_ws;  // N2P*DPROJ bf16 = 11.27 MB
  float* partials = (float*)((char*)d_ws + (size_t)N2P * DPROJ * sizeof(bf16));
  // partials: N1 * NBX * 6 floats (~1.06 MB), fully written -> no memset

  normalize_kernel<<<N2P, 256, 0, stream>>>(q, vc, kn, out);

  dim3 grid(N2P / BN, N1 / BM);
  gemm_loss_kernel<<<grid, 256, 0, stream>>>(kn, labels, partials);

  finalize_kernel<<<4, 256, 0, stream>>>(partials, labels, depth, out);
}

// Round 11
// 52.980 us; speedup vs baseline: 1.1853x; 1.0832x over previous
//
#include <hip/hip_runtime.h>
#include <math.h>

#define N1 1024
#define DPROJ 1024
#define M_NODES 4368
#define N2 (N1 + M_NODES)      // 5392
#define N2P 5504               // padded to 43*128 for the GEMM
#define L_LEAVES 4096
#define INV_T (1.0f / 0.07f)
#define NBX 43                 // N2P / BN

typedef __bf16 bf16;
typedef __bf16 bf16x4v __attribute__((ext_vector_type(4)));
typedef __bf16 bf16x8 __attribute__((ext_vector_type(8)));
typedef float f32x4 __attribute__((ext_vector_type(4)));

// ---------------------------------------------------------------------------
// Kernel A: fused normalize + bf16 cast. kn[row] = row/max(||row||,1e-12);
// rows >= N2 zero-filled (GEMM padding). Block 0 also zeroes d_out.
// ---------------------------------------------------------------------------
__global__ __launch_bounds__(256) void normalize_kernel(
    const float* __restrict__ q, const float* __restrict__ vc,
    bf16* __restrict__ kn, float* __restrict__ out) {
  const int row = blockIdx.x;
  if (row == 0 && threadIdx.x == 0) { out[0] = 0.f; out[1] = 0.f; }
  bf16x4v* dst = (bf16x4v*)(kn + (size_t)row * DPROJ);
  if (row >= N2) {
    bf16x4v z = {(bf16)0.f, (bf16)0.f, (bf16)0.f, (bf16)0.f};
    dst[threadIdx.x] = z;
    return;
  }
  const float* src = (row < N1) ? q + (size_t)row * DPROJ
                                : vc + (size_t)(row - N1) * DPROJ;
  float4 v = ((const float4*)src)[threadIdx.x];
  float s = v.x * v.x + v.y * v.y + v.z * v.z + v.w * v.w;
  for (int off = 32; off > 0; off >>= 1) s += __shfl_down(s, off);
  __shared__ float wsum[4];
  const int lane = threadIdx.x & 63, wid = threadIdx.x >> 6;
  if (lane == 0) wsum[wid] = s;
  __syncthreads();
  const float tot = wsum[0] + wsum[1] + wsum[2] + wsum[3];
  const float inv = 1.0f / fmaxf(sqrtf(tot), 1e-12f);
  bf16x4v o = {(bf16)(v.x * inv), (bf16)(v.y * inv), (bf16)(v.z * inv),
               (bf16)(v.w * inv)};
  dst[threadIdx.x] = o;
}

// ---------------------------------------------------------------------------
// Kernel B: fused GEMM + loss partials. R8 geometry + sync exactly (64x128
// tile, BK=32, 2x2 waves of 32x64, 3 LDS buffers, 2-ahead prefetch,
// counted vmcnt(6), raw s_barriers) — best measured (55.0 us; R9 -wave
// variant and R10 4-buf/1-barrier both regressed).
// R11 changes:
//  (1) T1 chunked XCD swizzle: 688 = 8 XCDs x 86. Default x-major puts a
//      shifting bx-set on each XCD (43 = 3 mod 8) -> every XCD streams all
//      43 B-panels (11 MB) through its 4 MB L2. Remap wg -> vid so each
//      XCD owns a contiguous (bx,by) chunk: ~6 B-panels + 16 A-panels =
//      3.4 MB, L2-resident -> staging becomes L2-hit latency.
//  (2) lab_s[1024] -> lab_r[64]+lab_c[128]: LDS 43.75 -> 39.75 KB ->
//      4 blocks/CU (16 waves/CU) for more TLP.
// ---------------------------------------------------------------------------
#define BM 64
#define BN 128
#define BK 32
#define NT (DPROJ / BK)

__device__ __forceinline__ void gload16(const bf16* g, bf16* l) {
  __builtin_amdgcn_global_load_lds(
      (const __attribute__((address_space(1))) void*)g,
      (__attribute__((address_space(3))) void*)l, 16, 0, 0);
}

__global__ __launch_bounds__(256, 4) void gemm_loss_kernel(
    const bf16* __restrict__ kn, const int* __restrict__ labels,
    float* __restrict__ partials) {
  __shared__ bf16 As[3][BM][BK];         // 12 KB
  __shared__ bf16 Bs[3][BN][BK];         // 24 KB
  __shared__ int lab_r[BM];              // 256 B
  __shared__ int lab_c[BN];              // 512 B
  __shared__ float blk_part[BM][2][6];   // 3 KB
  // Chunked bijective XCD swizzle (688 = 8 x 86): xcd = wg&7 owns vids
  // [86*xcd, 86*xcd+86) -> contiguous (bx,by) chunk, y-fastest.
  const int wg = blockIdx.y * NBX + blockIdx.x;
  const int vid = (wg & 7) * 86 + (wg >> 3);
  const int bx = vid >> 4;          // 0..42
  const int by = vid & 15;          // 0..15
  const int j0 = bx * BN;
  const int i0 = by * BM;
  const int t = threadIdx.x;
  const int lane = t & 63, w = t >> 6;
  const int wm = w >> 1, wn = w & 1;   // wave grid 2x2, wave tile 32x64

  if (t < BM) lab_r[t] = labels[i0 + t];
  if (t < BN && j0 + t < N1) lab_c[t] = labels[j0 + t];

  f32x4 acc[2][4] = {};

  // Staging: wave w stages A rows [16w,16w+16) and B rows {16w, 16w+64}.
  // lane -> row = lane>>2, LDS 16B-slot = lane&3 (linear dest).
  // Global 16B-slot pre-swizzled: (lane&3) ^ ((row>>1)&3) = ^((lane>>3)&3).
  const int rik = lane >> 2;
  const int kswz = ((lane & 3) ^ ((lane >> 3) & 3)) * 8;
  const bf16* gA = kn + (size_t)(i0 + w * 16 + rik) * DPROJ + kswz;
  const bf16* gB0 = kn + (size_t)(j0 + w * 16 + rik) * DPROJ + kswz;
  const bf16* gB1 = gB0 + (size_t)64 * DPROJ;

  // Fragment reads: row = base + (lane&15), logical k-slot g = lane>>4 ->
  // LDS slot g ^ ((row>>1)&3). Conflict-free (R7-measured).
  const int ar = wm * 32 + (lane & 15);
  const int br = wn * 64 + (lane & 15);
  const int kf = (((lane >> 4) ^ ((lane >> 1) & 3))) * 8;

#define STAGE(buf, k0)                            \
  do {                                            \
    gload16(gA + (k0), &As[buf][w * 16][0]);      \
    gload16(gB0 + (k0), &Bs[buf][w * 16][0]);     \
    gload16(gB1 + (k0), &Bs[buf][w * 16 + 64][0]);\
  } while (0)

  // Prologue: stage tiles 0,1 into bufs 0,1; full drain (labels visible).
  STAGE(0, 0);
  STAGE(1, BK);
  __syncthreads();

#pragma unroll 3
  for (int it = 0; it < NT; ++it) {
    const int cur = it % 3;
    if (it + 2 < NT) {
      STAGE((it + 2) % 3, (it + 2) * BK);
      asm volatile("s_waitcnt vmcnt(6)" ::: "memory");   // oldest 3 = tile it
    } else if (it + 1 < NT) {
      asm volatile("s_waitcnt vmcnt(3)" ::: "memory");
    } else {
      asm volatile("s_waitcnt vmcnt(0)" ::: "memory");
    }
    __builtin_amdgcn_s_barrier();   // all waves' tile-it loads complete

    bf16x8 a[2], b[4];
#pragma unroll
    for (int m = 0; m < 2; ++m)
      a[m] = *(const bf16x8*)&As[cur][ar + m * 16][kf];
#pragma unroll
    for (int n = 0; n < 4; ++n)
      b[n] = *(const bf16x8*)&Bs[cur][br + n * 16][kf];
#pragma unroll
    for (int m = 0; m < 2; ++m)
#pragma unroll
      for (int n = 0; n < 4; ++n)
        acc[m][n] = __builtin_amdgcn_mfma_f32_16x16x32_bf16(
            a[m], b[n], acc[m][n], 0, 0, 0);

    __builtin_amdgcn_s_barrier();   // reads of buf[cur] done -> reusable
  }

  // Fused epilogue. C/D layout: col=lane&15, row=(lane>>4)*4+j [m89].
  const int g = lane >> 4;
  const int p = lane & 15;
#pragma unroll
  for (int m = 0; m < 2; ++m) {
#pragma unroll
    for (int j = 0; j < 4; ++j) {
      const int rloc = wm * 32 + m * 16 + g * 4 + j;
      const int lab = lab_r[rloc];
      const int a2 = lab >> 4, a1 = lab >> 8;
      float ps0 = 0, ps1 = 0, ps2 = 0, ns0 = 0, ns1 = 0, ns2 = 0;
#pragma unroll
      for (int n = 0; n < 4; ++n) {
        const int cloc = wn * 64 + n * 16 + p;
        const int gc = j0 + cloc;
        if (gc < N2) {
          const int nid = (gc < N1) ? lab_c[cloc] : (gc - N1);
          const bool isLeaf = nid < L_LEAVES;
          const bool isD2 = (nid >= L_LEAVES) && (nid < L_LEAVES + 256);
          const bool eq = (nid == lab);
          const bool inS2 =
              (nid == L_LEAVES + a2) || (isLeaf && ((nid >> 4) == a2));
          const bool inS1 = (nid == L_LEAVES + 256 + a1) ||
                            (isD2 && (((nid - L_LEAVES) >> 4) == a1)) ||
                            (isLeaf && ((nid >> 8) == a1));
          const float v = acc[m][n][j] * INV_T;
          const float e = __expf(v);
          if (eq) ps2 += v; else ns2 += e;
          if (inS2) { if (!eq) ps1 += v; } else ns1 += e;
          if (inS1) { if (!inS2) ps0 += v; } else ns0 += e;
        }
      }
#pragma unroll
      for (int msk = 1; msk < 16; msk <<= 1) {
        ps0 += __shfl_xor(ps0, msk);
        ps1 += __shfl_xor(ps1, msk);
        ps2 += __shfl_xor(ps2, msk);
        ns0 += __shfl_xor(ns0, msk);
        ns1 += __shfl_xor(ns1, msk);
        ns2 += __shfl_xor(ns2, msk);
      }
      if (p == 0) {
        float* d = &blk_part[rloc][wn][0];
        d[0] = ps0; d[1] = ps1; d[2] = ps2;
        d[3] = ns0; d[4] = ns1; d[5] = ns2;
      }
    }
  }
  __syncthreads();
  for (int idx = t; idx < BM * 6; idx += 256) {
    const int r = idx / 6, k = idx % 6;
    const float val = blk_part[r][0][k] + blk_part[r][1][k];
    partials[((size_t)(i0 + r) * NBX + bx) * 6 + k] = val;
  }
}

// ---------------------------------------------------------------------------
// Kernel C: finalize. LDS label histogram, sum 43 slices/row, CE with
// analytic counts: |eq|=hist[lab]+1; |S2|=hist2+17; |S1|=hist1+273.
// Masked entries contribute exp(0)=1 -> +|set| in the LSE.
// ---------------------------------------------------------------------------
__global__ __launch_bounds__(256) void finalize_kernel(
    const float* __restrict__ partials, const int* __restrict__ labels,
    const float* __restrict__ depth, float* __restrict__ out) {
  __shared__ int hist_s[M_NODES];   // 17.4 KB
  const int t = threadIdx.x;
  for (int i = t; i < M_NODES; i += 256) hist_s[i] = 0;
  __syncthreads();
  for (int i = t; i < N1; i += 256) {
    const int lb = labels[i];
    atomicAdd(&hist_s[lb], 1);
    atomicAdd(&hist_s[L_LEAVES + (lb >> 4)], 1);
    atomicAdd(&hist_s[L_LEAVES + 256 + (lb >> 8)], 1);
  }
  __syncthreads();

  const int row = blockIdx.x * 256 + t;
  const int lab = labels[row];
  const int a2 = lab >> 4, a1 = lab >> 8;
  const int cEq = hist_s[lab] + 1;
  const int cS2 = hist_s[L_LEAVES + a2] + 17;
  const int cS1 = hist_s[L_LEAVES + 256 + a1] + 273;
  float ps0 = 0, ps1 = 0, ps2 = 0, ns0 = 0, ns1 = 0, ns2 = 0;
  const float* pp = partials + (size_t)row * NBX * 6;
  for (int b = 0; b < NBX; ++b) {
    ps0 += pp[b * 6 + 0];
    ps1 += pp[b * 6 + 1];
    ps2 += pp[b * 6 + 2];
    ns0 += pp[b * 6 + 3];
    ns1 += pp[b * 6 + 4];
    ns2 += pp[b * 6 + 5];
  }
  float ce = 0.f;
  {
    float pl = ps2 / fmaxf((float)cEq, 1e-6f);
    ce += logf(ns2 + (float)cEq + __expf(pl)) - pl;
  }
  {
    float pl = ps1 / fmaxf((float)(cS2 - cEq), 1e-6f);
    ce += logf(ns1 + (float)cS2 + __expf(pl)) - pl;
  }
  {
    float pl = ps0 / fmaxf((float)(cS1 - cS2), 1e-6f);
    ce += logf(ns0 + (float)cS1 + __expf(pl)) - pl;
  }
  float contrib = ce / depth[lab] * (3.0f / (float)N1);
  for (int off = 32; off > 0; off >>= 1) contrib += __shfl_down(contrib, off);
  __shared__ float wsum[4];
  const int lane = t & 63, wid = t >> 6;
  if (lane == 0) wsum[wid] = contrib;
  __syncthreads();
  if (t == 0) {
    const float tot = wsum[0] + wsum[1] + wsum[2] + wsum[3];
    atomicAdd(&out[0], tot);
    atomicAdd(&out[1], tot);
  }
}

// ---------------------------------------------------------------------------
extern "C" void kernel_launch(void* const* d_in, const int* in_sizes, int n_in,
                              void* d_out, int out_size, void* d_ws,
                              size_t ws_size, hipStream_t stream) {
  const float* q = (const float*)d_in[0];
  const float* vc = (const float*)d_in[1];
  const int* labels = (const int*)d_in[2];
  const float* depth = (const float*)d_in[6];
  float* out = (float*)d_out;

  bf16* kn = (bf16*)d_ws;  // N2P*DPROJ bf16 = 11.27 MB
  float* partials = (float*)((char*)d_ws + (size_t)N2P * DPROJ * sizeof(bf16));
  // partials: N1 * NBX * 6 floats (~1.06 MB), fully written -> no memset

  normalize_kernel<<<N2P, 256, 0, stream>>>(q, vc, kn, out);

  dim3 grid(NBX, N1 / BM);
  gemm_loss_kernel<<<grid, 256, 0, stream>>>(kn, labels, partials);

  finalize_kernel<<<4, 256, 0, stream>>>(partials, labels, depth, out);
}

// Round 12
// 48.816 us; speedup vs baseline: 1.2864x; 1.0853x over previous
//
#include <hip/hip_runtime.h>
#include <math.h>

#define N1 1024
#define DPROJ 1024
#define M_NODES 4368
#define N2 (N1 + M_NODES)      // 5392
#define N2P 5504               // padded to 43*128 for the GEMM
#define L_LEAVES 4096
#define INV_T (1.0f / 0.07f)
#define NBX 43                 // N2P / BN

typedef __bf16 bf16;
typedef __bf16 bf16x4v __attribute__((ext_vector_type(4)));
typedef __bf16 bf16x8 __attribute__((ext_vector_type(8)));
typedef float f32x4 __attribute__((ext_vector_type(4)));

// ---------------------------------------------------------------------------
// Kernel A: fused normalize + bf16 cast. kn[row] = row/max(||row||,1e-12);
// rows >= N2 zero-filled (GEMM padding). Block 0 also zeroes d_out.
// ---------------------------------------------------------------------------
__global__ __launch_bounds__(256) void normalize_kernel(
    const float* __restrict__ q, const float* __restrict__ vc,
    bf16* __restrict__ kn, float* __restrict__ out) {
  const int row = blockIdx.x;
  if (row == 0 && threadIdx.x == 0) { out[0] = 0.f; out[1] = 0.f; }
  bf16x4v* dst = (bf16x4v*)(kn + (size_t)row * DPROJ);
  if (row >= N2) {
    bf16x4v z = {(bf16)0.f, (bf16)0.f, (bf16)0.f, (bf16)0.f};
    dst[threadIdx.x] = z;
    return;
  }
  const float* src = (row < N1) ? q + (size_t)row * DPROJ
                                : vc + (size_t)(row - N1) * DPROJ;
  float4 v = ((const float4*)src)[threadIdx.x];
  float s = v.x * v.x + v.y * v.y + v.z * v.z + v.w * v.w;
  for (int off = 32; off > 0; off >>= 1) s += __shfl_down(s, off);
  __shared__ float wsum[4];
  const int lane = threadIdx.x & 63, wid = threadIdx.x >> 6;
  if (lane == 0) wsum[wid] = s;
  __syncthreads();
  const float tot = wsum[0] + wsum[1] + wsum[2] + wsum[3];
  const float inv = 1.0f / fmaxf(sqrtf(tot), 1e-12f);
  bf16x4v o = {(bf16)(v.x * inv), (bf16)(v.y * inv), (bf16)(v.z * inv),
               (bf16)(v.w * inv)};
  dst[threadIdx.x] = o;
}

// ---------------------------------------------------------------------------
// Kernel B: fused GEMM + loss partials.
// R12 change (ONLY): BK 32 -> 64. 16 K-iterations, 2 LDS buffers, 1-ahead
// prefetch, counted vmcnt(6) + raw barriers (R8 sync), XCD swizzle (R11).
// Halves the barrier count (32 pairs vs 64) — m233: stage+vmcnt+barrier
// overhead dominates 2-phase loops; per-barrier work doubles here.
// LDS swizzle for 128B rows: logical slot s (=kk*4+g) stored at physical
// s ^ (row&7); 16-lane read group spans all 32 banks 2-way (free, m136).
// Staging pre-swizzles global source by the same involution (within-row
// permutation -> coalescing intact).  51.75 KB LDS -> 3 blocks/CU.
// ---------------------------------------------------------------------------
#define BM 64
#define BN 128
#define BK 64
#define NT (DPROJ / BK)

__device__ __forceinline__ void gload16(const bf16* g, bf16* l) {
  __builtin_amdgcn_global_load_lds(
      (const __attribute__((address_space(1))) void*)g,
      (__attribute__((address_space(3))) void*)l, 16, 0, 0);
}

__global__ __launch_bounds__(256, 3) void gemm_loss_kernel(
    const bf16* __restrict__ kn, const int* __restrict__ labels,
    float* __restrict__ partials) {
  __shared__ bf16 As[2][BM][BK];         // 16 KB
  __shared__ bf16 Bs[2][BN][BK];         // 32 KB
  __shared__ int lab_r[BM];              // 256 B
  __shared__ int lab_c[BN];              // 512 B
  __shared__ float blk_part[BM][2][6];   // 3 KB
  // Chunked bijective XCD swizzle (688 = 8 x 86), y-fastest chunks.
  const int wg = blockIdx.y * NBX + blockIdx.x;
  const int vid = (wg & 7) * 86 + (wg >> 3);
  const int bx = vid >> 4;          // 0..42
  const int by = vid & 15;          // 0..15
  const int j0 = bx * BN;
  const int i0 = by * BM;
  const int t = threadIdx.x;
  const int lane = t & 63, w = t >> 6;
  const int wm = w >> 1, wn = w & 1;   // wave grid 2x2, wave tile 32x64

  if (t < BM) lab_r[t] = labels[i0 + t];
  if (t < BN && j0 + t < N1) lab_c[t] = labels[j0 + t];

  f32x4 acc[2][4] = {};

  // Staging at BK=64: one gload16 = 8 rows x 128 B. lane -> row = lane>>3,
  // physical 16B-slot = lane&7. Global slot pre-swizzled by row&7
  // (= (lane>>3)&7): s_src = (lane&7) ^ ((lane>>3)&7).
  const int rik = lane >> 3;
  const int kswz = ((lane & 7) ^ ((lane >> 3) & 7)) * 8;
  // Wave w: A rows [16w, 16w+16) (2 gloads), B rows [32w, 32w+32) (4).
  const bf16* gA0 = kn + (size_t)(i0 + w * 16 + rik) * DPROJ + kswz;
  const bf16* gA1 = gA0 + (size_t)8 * DPROJ;
  const bf16* gB0 = kn + (size_t)(j0 + w * 32 + rik) * DPROJ + kswz;
  const bf16* gB1 = gB0 + (size_t)8 * DPROJ;
  const bf16* gB2 = gB0 + (size_t)16 * DPROJ;
  const bf16* gB3 = gB0 + (size_t)24 * DPROJ;

  // Fragment reads: row = base + (lane&15) (bases mult of 16 -> row&7 =
  // lane&7); k-step kk in {0,1}, group g = lane>>4: logical slot kk*4+g,
  // physical slot = (kk*4+g) ^ (lane&7). Element offset = slot*8.
  const int ar = wm * 32 + (lane & 15);
  const int br = wn * 64 + (lane & 15);
  const int l7 = lane & 7;
  const int g4 = lane >> 4;
  const int kf0 = ((g4 ^ l7)) * 8;        // kk = 0
  const int kf1 = (((4 + g4) ^ l7)) * 8;  // kk = 1

#define STAGE(buf, k0)                             \
  do {                                             \
    gload16(gA0 + (k0), &As[buf][w * 16][0]);      \
    gload16(gA1 + (k0), &As[buf][w * 16 + 8][0]);  \
    gload16(gB0 + (k0), &Bs[buf][w * 32][0]);      \
    gload16(gB1 + (k0), &Bs[buf][w * 32 + 8][0]);  \
    gload16(gB2 + (k0), &Bs[buf][w * 32 + 16][0]); \
    gload16(gB3 + (k0), &Bs[buf][w * 32 + 24][0]); \
  } while (0)

  // Prologue: tile 0 into buf 0; full drain (labels visible too).
  STAGE(0, 0);
  __syncthreads();

#pragma unroll 2
  for (int it = 0; it < NT; ++it) {
    const int cur = it & 1;
    if (it + 1 < NT) {
      STAGE(cur ^ 1, (it + 1) * BK);
      asm volatile("s_waitcnt vmcnt(6)" ::: "memory");  // oldest 6 = tile it
    } else {
      asm volatile("s_waitcnt vmcnt(0)" ::: "memory");
    }
    __builtin_amdgcn_s_barrier();   // all waves' tile-it loads complete

    bf16x8 a0[2], a1[2], b0[4], b1[4];
#pragma unroll
    for (int m = 0; m < 2; ++m) {
      a0[m] = *(const bf16x8*)&As[cur][ar + m * 16][kf0];
      a1[m] = *(const bf16x8*)&As[cur][ar + m * 16][kf1];
    }
#pragma unroll
    for (int n = 0; n < 4; ++n) {
      b0[n] = *(const bf16x8*)&Bs[cur][br + n * 16][kf0];
      b1[n] = *(const bf16x8*)&Bs[cur][br + n * 16][kf1];
    }
#pragma unroll
    for (int m = 0; m < 2; ++m)
#pragma unroll
      for (int n = 0; n < 4; ++n) {
        acc[m][n] = __builtin_amdgcn_mfma_f32_16x16x32_bf16(
            a0[m], b0[n], acc[m][n], 0, 0, 0);
        acc[m][n] = __builtin_amdgcn_mfma_f32_16x16x32_bf16(
            a1[m], b1[n], acc[m][n], 0, 0, 0);
      }

    __builtin_amdgcn_s_barrier();   // reads of buf[cur] done -> reusable
  }

  // Fused epilogue. C/D layout: col=lane&15, row=(lane>>4)*4+j [m89].
  const int g = lane >> 4;
  const int p = lane & 15;
#pragma unroll
  for (int m = 0; m < 2; ++m) {
#pragma unroll
    for (int j = 0; j < 4; ++j) {
      const int rloc = wm * 32 + m * 16 + g * 4 + j;
      const int lab = lab_r[rloc];
      const int a2 = lab >> 4, a1 = lab >> 8;
      float ps0 = 0, ps1 = 0, ps2 = 0, ns0 = 0, ns1 = 0, ns2 = 0;
#pragma unroll
      for (int n = 0; n < 4; ++n) {
        const int cloc = wn * 64 + n * 16 + p;
        const int gc = j0 + cloc;
        if (gc < N2) {
          const int nid = (gc < N1) ? lab_c[cloc] : (gc - N1);
          const bool isLeaf = nid < L_LEAVES;
          const bool isD2 = (nid >= L_LEAVES) && (nid < L_LEAVES + 256);
          const bool eq = (nid == lab);
          const bool inS2 =
              (nid == L_LEAVES + a2) || (isLeaf && ((nid >> 4) == a2));
          const bool inS1 = (nid == L_LEAVES + 256 + a1) ||
                            (isD2 && (((nid - L_LEAVES) >> 4) == a1)) ||
                            (isLeaf && ((nid >> 8) == a1));
          const float v = acc[m][n][j] * INV_T;
          const float e = __expf(v);
          if (eq) ps2 += v; else ns2 += e;
          if (inS2) { if (!eq) ps1 += v; } else ns1 += e;
          if (inS1) { if (!inS2) ps0 += v; } else ns0 += e;
        }
      }
#pragma unroll
      for (int msk = 1; msk < 16; msk <<= 1) {
        ps0 += __shfl_xor(ps0, msk);
        ps1 += __shfl_xor(ps1, msk);
        ps2 += __shfl_xor(ps2, msk);
        ns0 += __shfl_xor(ns0, msk);
        ns1 += __shfl_xor(ns1, msk);
        ns2 += __shfl_xor(ns2, msk);
      }
      if (p == 0) {
        float* d = &blk_part[rloc][wn][0];
        d[0] = ps0; d[1] = ps1; d[2] = ps2;
        d[3] = ns0; d[4] = ns1; d[5] = ns2;
      }
    }
  }
  __syncthreads();
  for (int idx = t; idx < BM * 6; idx += 256) {
    const int r = idx / 6, k = idx % 6;
    const float val = blk_part[r][0][k] + blk_part[r][1][k];
    partials[((size_t)(i0 + r) * NBX + bx) * 6 + k] = val;
  }
}

// ---------------------------------------------------------------------------
// Kernel C: finalize. LDS label histogram, sum 43 slices/row, CE with
// analytic counts: |eq|=hist[lab]+1; |S2|=hist2+17; |S1|=hist1+273.
// Masked entries contribute exp(0)=1 -> +|set| in the LSE.
// ---------------------------------------------------------------------------
__global__ __launch_bounds__(256) void finalize_kernel(
    const float* __restrict__ partials, const int* __restrict__ labels,
    const float* __restrict__ depth, float* __restrict__ out) {
  __shared__ int hist_s[M_NODES];   // 17.4 KB
  const int t = threadIdx.x;
  for (int i = t; i < M_NODES; i += 256) hist_s[i] = 0;
  __syncthreads();
  for (int i = t; i < N1; i += 256) {
    const int lb = labels[i];
    atomicAdd(&hist_s[lb], 1);
    atomicAdd(&hist_s[L_LEAVES + (lb >> 4)], 1);
    atomicAdd(&hist_s[L_LEAVES + 256 + (lb >> 8)], 1);
  }
  __syncthreads();

  const int row = blockIdx.x * 256 + t;
  const int lab = labels[row];
  const int a2 = lab >> 4, a1 = lab >> 8;
  const int cEq = hist_s[lab] + 1;
  const int cS2 = hist_s[L_LEAVES + a2] + 17;
  const int cS1 = hist_s[L_LEAVES + 256 + a1] + 273;
  float ps0 = 0, ps1 = 0, ps2 = 0, ns0 = 0, ns1 = 0, ns2 = 0;
  const float* pp = partials + (size_t)row * NBX * 6;
  for (int b = 0; b < NBX; ++b) {
    ps0 += pp[b * 6 + 0];
    ps1 += pp[b * 6 + 1];
    ps2 += pp[b * 6 + 2];
    ns0 += pp[b * 6 + 3];
    ns1 += pp[b * 6 + 4];
    ns2 += pp[b * 6 + 5];
  }
  float ce = 0.f;
  {
    float pl = ps2 / fmaxf((float)cEq, 1e-6f);
    ce += logf(ns2 + (float)cEq + __expf(pl)) - pl;
  }
  {
    float pl = ps1 / fmaxf((float)(cS2 - cEq), 1e-6f);
    ce += logf(ns1 + (float)cS2 + __expf(pl)) - pl;
  }
  {
    float pl = ps0 / fmaxf((float)(cS1 - cS2), 1e-6f);
    ce += logf(ns0 + (float)cS1 + __expf(pl)) - pl;
  }
  float contrib = ce / depth[lab] * (3.0f / (float)N1);
  for (int off = 32; off > 0; off >>= 1) contrib += __shfl_down(contrib, off);
  __shared__ float wsum[4];
  const int lane = t & 63, wid = t >> 6;
  if (lane == 0) wsum[wid] = contrib;
  __syncthreads();
  if (t == 0) {
    const float tot = wsum[0] + wsum[1] + wsum[2] + wsum[3];
    atomicAdd(&out[0], tot);
    atomicAdd(&out[1], tot);
  }
}

// ---------------------------------------------------------------------------
extern "C" void kernel_launch(void* const* d_in, const int* in_sizes, int n_in,
                              void* d_out, int out_size, void* d_ws,
                              size_t ws_size, hipStream_t stream) {
  const float* q = (const float*)d_in[0];
  const float* vc = (const float*)d_in[1];
  const int* labels = (const int*)d_in[2];
  const float* depth = (const float*)d_in[6];
  float* out = (float*)d_out;

  bf16* kn = (bf16*)d_ws;  // N2P*DPROJ bf16 = 11.27 MB
  float* partials = (float*)((char*)d_ws + (size_t)N2P * DPROJ * sizeof(bf16));
  // partials: N1 * NBX * 6 floats (~1.06 MB), fully written -> no memset

  normalize_kernel<<<N2P, 256, 0, stream>>>(q, vc, kn, out);

  dim3 grid(NBX, N1 / BM);
  gemm_loss_kernel<<<grid, 256, 0, stream>>>(kn, labels, partials);

  finalize_kernel<<<4, 256, 0, stream>>>(partials, labels, depth, out);
}